// Round 7
// baseline (152.779 us; speedup 1.0000x reference)
//
#include <hip/hip_runtime.h>

typedef float f32x2 __attribute__((ext_vector_type(2)));
typedef float f32x4 __attribute__((ext_vector_type(4)));
typedef short bf16x8 __attribute__((ext_vector_type(8)));

#define LL 512
#define M_ROWS 2048            // 4 * 512
#define KC 768                 // split-K: [hi|hi|lo] x [hi|lo|hi]

#if __has_builtin(__builtin_amdgcn_exp2f)
#define EXP2F __builtin_amdgcn_exp2f
#else
#define EXP2F exp2f
#endif
#define LOG2E 1.44269504088896340736f

__device__ __forceinline__ float quad_swap1(float x) {
    return __int_as_float(__builtin_amdgcn_mov_dpp(__float_as_int(x), 0xB1, 0xF, 0xF, true));
}
__device__ __forceinline__ float quad_swap2(float x) {
    return __int_as_float(__builtin_amdgcn_mov_dpp(__float_as_int(x), 0x4E, 0xF, 0xF, true));
}

__device__ __forceinline__ unsigned short bf16_rtne(float x) {
    unsigned u = __float_as_uint(x);
    return (unsigned short)((u + 0x7fffu + ((u >> 16) & 1u)) >> 16);
}
__device__ __forceinline__ float bf16_to_f(unsigned short h) {
    return __uint_as_float((unsigned)h << 16);
}

// ---------------------------------------------------------------------------
// Kernel 0: split fp32 -> bf16 (hi, lo) concatenated along K. (unchanged)
// ---------------------------------------------------------------------------
__global__ __launch_bounds__(64) void split_bf16(
    const float* __restrict__ X, const float* __restrict__ Wq,
    const float* __restrict__ Wk, const float* __restrict__ Wv,
    unsigned short* __restrict__ Xc, unsigned short* __restrict__ Wc)
{
    const int row = blockIdx.x;
    const int t = threadIdx.x;
    const float* src;
    unsigned short* hi1; unsigned short* hi2; unsigned short* lo1;
    if (row < M_ROWS) {
        src = X + (size_t)row * 256;
        hi1 = Xc + (size_t)row * KC;
        hi2 = hi1 + 256;
        lo1 = hi1 + 512;
    } else {
        const int n = row - M_ROWS;          // 0..767
        const int mat = n >> 8, c = n & 255;
        const int srow = (mat == 2) ? (((c & 31) << 3) | (c >> 5)) : c;
        src = (mat == 0 ? Wq : (mat == 1 ? Wk : Wv)) + (size_t)srow * 256;
        hi1 = Wc + (size_t)n * KC;
        lo1 = hi1 + 256;
        hi2 = hi1 + 512;
    }
    const f32x4 v = *(const f32x4*)(src + t * 4);
    ushort4 h, l;
    h.x = bf16_rtne(v.x); h.y = bf16_rtne(v.y); h.z = bf16_rtne(v.z); h.w = bf16_rtne(v.w);
    l.x = bf16_rtne(v.x - bf16_to_f(h.x));
    l.y = bf16_rtne(v.y - bf16_to_f(h.y));
    l.z = bf16_rtne(v.z - bf16_to_f(h.z));
    l.w = bf16_rtne(v.w - bf16_to_f(h.w));
    *(ushort4*)(hi1 + t * 4) = h;
    *(ushort4*)(hi2 + t * 4) = h;
    *(ushort4*)(lo1 + t * 4) = l;
}

// ---------------------------------------------------------------------------
// Kernel 1: Y = Xcat @ Wcat.T via bf16 MFMA. (unchanged)
// ---------------------------------------------------------------------------
__global__ __launch_bounds__(64) void qkv_mfma(
    const unsigned short* __restrict__ Xc, const unsigned short* __restrict__ Wc,
    float* __restrict__ Y)
{
    const int bid = blockIdx.x;
    const int m0 = (bid & 31) * 64;
    const int n0 = (bid >> 5) * 64;
    const int l = threadIdx.x;
    const int lr = l & 15;
    const int lk = (l >> 4) * 8;

    size_t aoff[4], boff[4];
#pragma unroll
    for (int i = 0; i < 4; ++i) {
        aoff[i] = (size_t)(m0 + i * 16 + lr) * KC + lk;
        boff[i] = (size_t)(n0 + i * 16 + lr) * KC + lk;
    }

    f32x4 acc[4][4];
#pragma unroll
    for (int i = 0; i < 4; ++i)
#pragma unroll
        for (int j = 0; j < 4; ++j) acc[i][j] = (f32x4){0.f, 0.f, 0.f, 0.f};

    bf16x8 A0[4], B0[4], A1[4], B1[4];
#pragma unroll
    for (int i = 0; i < 4; ++i) {
        A0[i] = *(const bf16x8*)(Xc + aoff[i]);
        B0[i] = *(const bf16x8*)(Wc + boff[i]);
    }

#pragma unroll 1
    for (int it = 0; it < 24; it += 2) {
        const int ks1 = (it + 1) * 32;
#pragma unroll
        for (int i = 0; i < 4; ++i) {
            A1[i] = *(const bf16x8*)(Xc + aoff[i] + ks1);
            B1[i] = *(const bf16x8*)(Wc + boff[i] + ks1);
        }
#pragma unroll
        for (int ai = 0; ai < 4; ++ai)
#pragma unroll
            for (int bi = 0; bi < 4; ++bi)
                acc[ai][bi] = __builtin_amdgcn_mfma_f32_16x16x32_bf16(
                    A0[ai], B0[bi], acc[ai][bi], 0, 0, 0);
        if (it + 2 < 24) {
            const int ks2 = (it + 2) * 32;
#pragma unroll
            for (int i = 0; i < 4; ++i) {
                A0[i] = *(const bf16x8*)(Xc + aoff[i] + ks2);
                B0[i] = *(const bf16x8*)(Wc + boff[i] + ks2);
            }
        }
#pragma unroll
        for (int ai = 0; ai < 4; ++ai)
#pragma unroll
            for (int bi = 0; bi < 4; ++bi)
                acc[ai][bi] = __builtin_amdgcn_mfma_f32_16x16x32_bf16(
                    A1[ai], B1[bi], acc[ai][bi], 0, 0, 0);
    }

    const int mat = n0 >> 8;
    float* Yb = Y + (size_t)mat * M_ROWS * 256;
#pragma unroll
    for (int ai = 0; ai < 4; ++ai)
#pragma unroll
        for (int bi = 0; bi < 4; ++bi) {
            const int col = (n0 & 255) + bi * 16 + lr;
#pragma unroll
            for (int r = 0; r < 4; ++r) {
                const int row = m0 + ai * 16 + (l >> 4) * 4 + r;
                Yb[(size_t)row * 256 + col] = acc[ai][bi][r];
            }
        }
}

// ---------------------------------------------------------------------------
// Kernel 2: fused grouped-MLP attention, LDS-staged K/V double-buffer.
// grid 512 = 4 batches x 128 q-tiles (4 q rows), 512 threads, 2 blocks/CU.
// thread = (dh = t&3, g = (t>>2)&7, p = t>>5: row 0..15 within k-tile).
// Thread's d-slice (group g): {g*32+dh*4+j} U {g*32+16+dh*4+j}, j=0..3 —
// staged into LDS so ds_read_b128 is stride-16 conflict-free.
// NOTE: w_mlp has 32 entries indexed by WITHIN-GROUP d (shared across g).
// ---------------------------------------------------------------------------
__global__ __launch_bounds__(512, 4) void attn_fused(
    const float* __restrict__ Y,
    const float* __restrict__ w_mlp, const float* __restrict__ b_mlp,
    float* __restrict__ out)
{
    const float* Qm = Y;
    const float* Km = Y + (size_t)M_ROWS * 256;
    const float* Vt = Y + (size_t)2 * M_ROWS * 256;

    const int bid = blockIdx.x;
    const int b = bid & 3;
    const int q0 = (bid >> 2) * 4;

    const int t = threadIdx.x;
    const int dh = t & 3;
    const int lane32 = t & 31;               // g*4 + dh
    const int g = lane32 >> 2;
    const int p = t >> 5;                    // 0..15: row within k-tile

    union SMem {
        struct { float kb[2][16][256]; float vb[2][16][256]; } s;  // 64 KB
        float accbuf[16][32][37];                                  // 75776 B
    };
    __shared__ SMem sm;

    const int dA = g * 32 + dh * 4;          // first 4-d chunk (global col)
    const int dB = dA + 16;                  // second 4-d chunk (global col)
    const float bias4 = b_mlp[0] * (LOG2E * 0.25f);

    f32x2 w2[4];
    {
        // w_mlp indexed by within-group d: dh*4..+3 and dh*4+16..+3
        f32x4 wa = *(const f32x4*)(w_mlp + dh * 4);
        f32x4 wb = *(const f32x4*)(w_mlp + dh * 4 + 16);
        wa *= LOG2E; wb *= LOG2E;
        w2[0] = __builtin_shufflevector(wa, wa, 0, 1);
        w2[1] = __builtin_shufflevector(wa, wa, 2, 3);
        w2[2] = __builtin_shufflevector(wb, wb, 0, 1);
        w2[3] = __builtin_shufflevector(wb, wb, 2, 3);
    }

    f32x2 qr2[4][4];
#pragma unroll
    for (int q = 0; q < 4; ++q) {
        const float* qp = Qm + ((size_t)(b * LL) + q0 + q) * 256;
        f32x4 qa = *(const f32x4*)(qp + dA);
        f32x4 qb = *(const f32x4*)(qp + dB);
        qr2[q][0] = __builtin_shufflevector(qa, qa, 0, 1);
        qr2[q][1] = __builtin_shufflevector(qa, qa, 2, 3);
        qr2[q][2] = __builtin_shufflevector(qb, qb, 0, 1);
        qr2[q][3] = __builtin_shufflevector(qb, qb, 2, 3);
    }

    f32x2 acc2[4][4];
#pragma unroll
    for (int q = 0; q < 4; ++q)
#pragma unroll
        for (int j = 0; j < 4; ++j) acc2[q][j] = (f32x2){0.f, 0.f};
    float l[4] = {0.f, 0.f, 0.f, 0.f};

    // ---- staging assignment: 2048 16B-chunks per tile, 4 per thread ----
    const float* gsrc[4];
    float* ldst0[4];
    float* ldst1[4];
#pragma unroll
    for (int r = 0; r < 4; ++r) {
        const int id = t + 512 * r;          // 0..2047
        const int isv = id >> 10;            // 0: K, 1: V
        const int rid = id & 1023;
        const int row = rid >> 6;            // 0..15
        const int c = rid & 63;              // 16B chunk within row
        const int gg = c >> 3, c7 = c & 7;
        const int cp = (c7 < 4) ? (4 * gg + c7) : (28 + 4 * gg + c7);  // swizzle
        gsrc[r] = (isv ? Vt : Km) + ((size_t)(b * LL) + row) * 256 + 4 * c;
        ldst0[r] = isv ? &sm.s.vb[0][row][4 * cp] : &sm.s.kb[0][row][4 * cp];
        ldst1[r] = isv ? &sm.s.vb[1][row][4 * cp] : &sm.s.kb[1][row][4 * cp];
    }

    // ---- preload tile 0 ----
    {
        f32x4 st[4];
#pragma unroll
        for (int r = 0; r < 4; ++r) st[r] = *(const f32x4*)gsrc[r];
#pragma unroll
        for (int r = 0; r < 4; ++r) *(f32x4*)ldst0[r] = st[r];
    }
    __syncthreads();

    const f32x2 z2 = {0.f, 0.f};
#pragma unroll 1
    for (int tile = 0; tile < 32; ++tile) {
        const int buf = tile & 1;
        f32x4 st[4];
        if (tile < 31) {
            const size_t adv = (size_t)(tile + 1) * 16 * 256;
#pragma unroll
            for (int r = 0; r < 4; ++r) st[r] = *(const f32x4*)(gsrc[r] + adv);
        }
        // ---- compute: k = tile*16 + p, 4 q's ----
        {
            const float* kr = &sm.s.kb[buf][p][0];
            const float* vr = &sm.s.vb[buf][p][0];
            const f32x4 ka = *(const f32x4*)(kr + 4 * lane32);
            const f32x4 kb_ = *(const f32x4*)(kr + 4 * lane32 + 128);
            const f32x4 va = *(const f32x4*)(vr + 4 * lane32);
            const f32x4 vb_ = *(const f32x4*)(vr + 4 * lane32 + 128);
            f32x2 k2[4] = {__builtin_shufflevector(ka, ka, 0, 1),
                           __builtin_shufflevector(ka, ka, 2, 3),
                           __builtin_shufflevector(kb_, kb_, 0, 1),
                           __builtin_shufflevector(kb_, kb_, 2, 3)};
            f32x2 v2[4] = {__builtin_shufflevector(va, va, 0, 1),
                           __builtin_shufflevector(va, va, 2, 3),
                           __builtin_shufflevector(vb_, vb_, 0, 1),
                           __builtin_shufflevector(vb_, vb_, 2, 3)};
#pragma unroll
            for (int q = 0; q < 4; ++q) {
                f32x2 s2 = {bias4, 0.f};
#pragma unroll
                for (int j = 0; j < 4; ++j) {
                    f32x2 d2 = qr2[q][j] - k2[j];
                    f32x2 r2 = __builtin_elementwise_max(d2, z2);
                    s2 += w2[j] * r2;
                }
                float s = s2.x + s2.y;
                s += quad_swap1(s);
                s += quad_swap2(s);
                s = fmaxf(s, 0.f);
                const float e = EXP2F(s);
                l[q] += e;
                const f32x2 e2 = {e, e};
#pragma unroll
                for (int j = 0; j < 4; ++j) acc2[q][j] += e2 * v2[j];
            }
        }
        if (tile < 31) {
#pragma unroll
            for (int r = 0; r < 4; ++r)
                *(f32x4*)(buf ? ldst0[r] : ldst1[r]) = st[r];
        }
        __syncthreads();
    }

    // ---- epilogue: 16-phase LDS reduction (accbuf overlays staging) ----
    {
        float* rowp = &sm.accbuf[p][lane32][0];
#pragma unroll
        for (int qq = 0; qq < 4; ++qq)
#pragma unroll
            for (int j = 0; j < 4; ++j)
                *(f32x2*)(rowp + qq * 8 + j * 2) = acc2[qq][j];
        if (dh == 0) {
#pragma unroll
            for (int qq = 0; qq < 4; ++qq) sm.accbuf[p][lane32][32 + qq] = l[qq];
        }
    }
    __syncthreads();

    const int c_o = t & 255;
    const int g_o = c_o & 7, dd = c_o >> 3;          // dd: within-group d 0..31
    const int dhp = (dd & 15) >> 2;                  // owning dh
    const int jslot = (dd & 3) + 4 * (dd >> 4);      // slot within thread's 8
    const int rowb = g_o * 4 + dhp;
    const int qsel = t >> 8;                         // 0..1
#pragma unroll
    for (int h = 0; h < 2; ++h) {
        const int qh = qsel + 2 * h;                 // 0..3
        float s = 0.f, ls = 0.f;
#pragma unroll
        for (int pp = 0; pp < 16; ++pp) {
            s  += sm.accbuf[pp][rowb][qh * 8 + jslot];
            ls += sm.accbuf[pp][g_o * 4][32 + qh];
        }
        out[((size_t)(b * LL) + q0 + qh) * 256 + c_o] = s / ls;
    }
}

// ---------------------------------------------------------------------------
extern "C" void kernel_launch(void* const* d_in, const int* in_sizes, int n_in,
                              void* d_out, int out_size, void* d_ws, size_t ws_size,
                              hipStream_t stream) {
    (void)in_sizes; (void)n_in; (void)out_size; (void)ws_size;
    const float* x     = (const float*)d_in[0];
    const float* Wq    = (const float*)d_in[1];
    const float* Wk    = (const float*)d_in[2];
    const float* Wv    = (const float*)d_in[3];
    const float* w_mlp = (const float*)d_in[4];
    const float* b_mlp = (const float*)d_in[5];
    float* outp = (float*)d_out;

    float* Y = (float*)d_ws;                                   // 6 MB
    unsigned short* Xc = (unsigned short*)((char*)d_ws + (size_t)6291456);      // 3 MB
    unsigned short* Wc = (unsigned short*)((char*)d_ws + (size_t)6291456 + 3145728); // 1.125 MB

    split_bf16<<<dim3(M_ROWS + 768), 64, 0, stream>>>(x, Wq, Wk, Wv, Xc, Wc);
    qkv_mfma<<<dim3(384), 64, 0, stream>>>(Xc, Wc, Y);
    attn_fused<<<dim3(512), 512, 0, stream>>>(Y, w_mlp, b_mlp, outp);
}

// Round 8
// 118.164 us; speedup vs baseline: 1.2929x; 1.2929x over previous
//
#include <hip/hip_runtime.h>

typedef float f32x2 __attribute__((ext_vector_type(2)));
typedef float f32x4 __attribute__((ext_vector_type(4)));
typedef short bf16x8 __attribute__((ext_vector_type(8)));
typedef _Float16 h16x2 __attribute__((ext_vector_type(2)));
typedef _Float16 h16x8 __attribute__((ext_vector_type(8)));

#define LL 512
#define M_ROWS 2048            // 4 * 512
#define KC 768                 // split-K: [hi|hi|lo] x [hi|lo|hi]

#if __has_builtin(__builtin_amdgcn_exp2f)
#define EXP2F __builtin_amdgcn_exp2f
#else
#define EXP2F exp2f
#endif
#define LOG2E 1.44269504088896340736f

__device__ __forceinline__ float quad_swap1(float x) {
    return __int_as_float(__builtin_amdgcn_mov_dpp(__float_as_int(x), 0xB1, 0xF, 0xF, true));
}
__device__ __forceinline__ float quad_swap2(float x) {
    return __int_as_float(__builtin_amdgcn_mov_dpp(__float_as_int(x), 0x4E, 0xF, 0xF, true));
}

__device__ __forceinline__ float fdot2f(h16x2 a, h16x2 b, float c) {
#if __has_builtin(__builtin_amdgcn_fdot2)
    return __builtin_amdgcn_fdot2(a, b, c, false);
#else
    return fmaf((float)a.x, (float)b.x, fmaf((float)a.y, (float)b.y, c));
#endif
}

__device__ __forceinline__ unsigned short bf16_rtne(float x) {
    unsigned u = __float_as_uint(x);
    return (unsigned short)((u + 0x7fffu + ((u >> 16) & 1u)) >> 16);
}
__device__ __forceinline__ float bf16_to_f(unsigned short h) {
    return __uint_as_float((unsigned)h << 16);
}

// ---------------------------------------------------------------------------
// Kernel 0: split fp32 -> bf16 (hi, lo) concatenated along K. (unchanged)
// ---------------------------------------------------------------------------
__global__ __launch_bounds__(64) void split_bf16(
    const float* __restrict__ X, const float* __restrict__ Wq,
    const float* __restrict__ Wk, const float* __restrict__ Wv,
    unsigned short* __restrict__ Xc, unsigned short* __restrict__ Wc)
{
    const int row = blockIdx.x;
    const int t = threadIdx.x;
    const float* src;
    unsigned short* hi1; unsigned short* hi2; unsigned short* lo1;
    if (row < M_ROWS) {
        src = X + (size_t)row * 256;
        hi1 = Xc + (size_t)row * KC;
        hi2 = hi1 + 256;
        lo1 = hi1 + 512;
    } else {
        const int n = row - M_ROWS;          // 0..767
        const int mat = n >> 8, c = n & 255;
        const int srow = (mat == 2) ? (((c & 31) << 3) | (c >> 5)) : c;
        src = (mat == 0 ? Wq : (mat == 1 ? Wk : Wv)) + (size_t)srow * 256;
        hi1 = Wc + (size_t)n * KC;
        lo1 = hi1 + 256;
        hi2 = hi1 + 512;
    }
    const f32x4 v = *(const f32x4*)(src + t * 4);
    ushort4 h, l;
    h.x = bf16_rtne(v.x); h.y = bf16_rtne(v.y); h.z = bf16_rtne(v.z); h.w = bf16_rtne(v.w);
    l.x = bf16_rtne(v.x - bf16_to_f(h.x));
    l.y = bf16_rtne(v.y - bf16_to_f(h.y));
    l.z = bf16_rtne(v.z - bf16_to_f(h.z));
    l.w = bf16_rtne(v.w - bf16_to_f(h.w));
    *(ushort4*)(hi1 + t * 4) = h;
    *(ushort4*)(hi2 + t * 4) = h;
    *(ushort4*)(lo1 + t * 4) = l;
}

// ---------------------------------------------------------------------------
// Kernel 1: Q,K (f16 out) and Vt (f32 out) via bf16 MFMA split-K GEMM.
// ---------------------------------------------------------------------------
__global__ __launch_bounds__(64) void qkv_mfma(
    const unsigned short* __restrict__ Xc, const unsigned short* __restrict__ Wc,
    _Float16* __restrict__ Qh, _Float16* __restrict__ Kh, float* __restrict__ Vt)
{
    const int bid = blockIdx.x;
    const int m0 = (bid & 31) * 64;
    const int n0 = (bid >> 5) * 64;
    const int l = threadIdx.x;
    const int lr = l & 15;
    const int lk = (l >> 4) * 8;

    size_t aoff[4], boff[4];
#pragma unroll
    for (int i = 0; i < 4; ++i) {
        aoff[i] = (size_t)(m0 + i * 16 + lr) * KC + lk;
        boff[i] = (size_t)(n0 + i * 16 + lr) * KC + lk;
    }

    f32x4 acc[4][4];
#pragma unroll
    for (int i = 0; i < 4; ++i)
#pragma unroll
        for (int j = 0; j < 4; ++j) acc[i][j] = (f32x4){0.f, 0.f, 0.f, 0.f};

    bf16x8 A0[4], B0[4], A1[4], B1[4];
#pragma unroll
    for (int i = 0; i < 4; ++i) {
        A0[i] = *(const bf16x8*)(Xc + aoff[i]);
        B0[i] = *(const bf16x8*)(Wc + boff[i]);
    }

#pragma unroll 1
    for (int it = 0; it < 24; it += 2) {
        const int ks1 = (it + 1) * 32;
#pragma unroll
        for (int i = 0; i < 4; ++i) {
            A1[i] = *(const bf16x8*)(Xc + aoff[i] + ks1);
            B1[i] = *(const bf16x8*)(Wc + boff[i] + ks1);
        }
#pragma unroll
        for (int ai = 0; ai < 4; ++ai)
#pragma unroll
            for (int bi = 0; bi < 4; ++bi)
                acc[ai][bi] = __builtin_amdgcn_mfma_f32_16x16x32_bf16(
                    A0[ai], B0[bi], acc[ai][bi], 0, 0, 0);
        if (it + 2 < 24) {
            const int ks2 = (it + 2) * 32;
#pragma unroll
            for (int i = 0; i < 4; ++i) {
                A0[i] = *(const bf16x8*)(Xc + aoff[i] + ks2);
                B0[i] = *(const bf16x8*)(Wc + boff[i] + ks2);
            }
        }
#pragma unroll
        for (int ai = 0; ai < 4; ++ai)
#pragma unroll
            for (int bi = 0; bi < 4; ++bi)
                acc[ai][bi] = __builtin_amdgcn_mfma_f32_16x16x32_bf16(
                    A1[ai], B1[bi], acc[ai][bi], 0, 0, 0);
    }

    const int mat = n0 >> 8;
    if (mat == 2) {
#pragma unroll
        for (int ai = 0; ai < 4; ++ai)
#pragma unroll
            for (int bi = 0; bi < 4; ++bi) {
                const int col = (n0 & 255) + bi * 16 + lr;
#pragma unroll
                for (int r = 0; r < 4; ++r) {
                    const int row = m0 + ai * 16 + (l >> 4) * 4 + r;
                    Vt[(size_t)row * 256 + col] = acc[ai][bi][r];
                }
            }
    } else {
        _Float16* Hb = (mat == 0) ? Qh : Kh;
#pragma unroll
        for (int ai = 0; ai < 4; ++ai)
#pragma unroll
            for (int bi = 0; bi < 4; ++bi) {
                const int col = (n0 & 255) + bi * 16 + lr;
#pragma unroll
                for (int r = 0; r < 4; ++r) {
                    const int row = m0 + ai * 16 + (l >> 4) * 4 + r;
                    Hb[(size_t)row * 256 + col] = (_Float16)acc[ai][bi][r];
                }
            }
    }
}

// ---------------------------------------------------------------------------
// Kernel 2: fused grouped-MLP attention — R5 skeleton, f16 score path.
// grid 512 = 4 batches x 128 q-tiles (4 q rows), 512 threads, 2 blocks/CU.
// thread = (dh = t&3: 8 contiguous d's, g = (t>>2)&7, p = t>>5: k-phase 0..15).
// Score: v_pk_add_f16/v_pk_max_f16/v_dot2_f32_f16; PV + softmax in f32.
// ---------------------------------------------------------------------------
__global__ __launch_bounds__(512, 4) void attn_fused(
    const _Float16* __restrict__ Qh, const _Float16* __restrict__ Kh,
    const float* __restrict__ Vt,
    const float* __restrict__ w_mlp, const float* __restrict__ b_mlp,
    float* __restrict__ out)
{
    const int bid = blockIdx.x;
    const int b = bid & 3;
    const int q0 = (bid >> 2) * 4;

    const int t = threadIdx.x;
    const int dh = t & 3;
    const int p = t >> 5;                    // 0..15
    const int lane32 = t & 31;               // g*4 + dh
    const int g = lane32 >> 2;

    __shared__ float accbuf[16][32][37];     // 75776 B (rows: 4q*8 + l[4])

    const int doff = g * 32 + dh * 8;
    const float bias4 = b_mlp[0] * (LOG2E * 0.25f);

    h16x2 w2[4];
    {
        f32x4 wa = *(const f32x4*)(w_mlp + dh * 8);
        f32x4 wb = *(const f32x4*)(w_mlp + dh * 8 + 4);
        wa *= LOG2E; wb *= LOG2E;
        w2[0] = (h16x2){(_Float16)wa.x, (_Float16)wa.y};
        w2[1] = (h16x2){(_Float16)wa.z, (_Float16)wa.w};
        w2[2] = (h16x2){(_Float16)wb.x, (_Float16)wb.y};
        w2[3] = (h16x2){(_Float16)wb.z, (_Float16)wb.w};
    }

    h16x2 qr2[4][4];
#pragma unroll
    for (int q = 0; q < 4; ++q) {
        const h16x8 qv = *(const h16x8*)(Qh + ((size_t)(b * LL) + q0 + q) * 256 + doff);
        qr2[q][0] = __builtin_shufflevector(qv, qv, 0, 1);
        qr2[q][1] = __builtin_shufflevector(qv, qv, 2, 3);
        qr2[q][2] = __builtin_shufflevector(qv, qv, 4, 5);
        qr2[q][3] = __builtin_shufflevector(qv, qv, 6, 7);
    }

    f32x2 acc2[4][4];
#pragma unroll
    for (int q = 0; q < 4; ++q)
#pragma unroll
        for (int j = 0; j < 4; ++j) acc2[q][j] = (f32x2){0.f, 0.f};
    float l[4] = {0.f, 0.f, 0.f, 0.f};

    const _Float16* kptr = Kh + ((size_t)(b * LL) + p) * 256 + doff;
    const float* vptr = Vt + ((size_t)(b * LL) + p) * 256 + doff;

    const h16x2 zh = {(_Float16)0.f, (_Float16)0.f};

    auto compute = [&](h16x8 kv, f32x4 va, f32x4 vb) {
        h16x2 k2[4] = {__builtin_shufflevector(kv, kv, 0, 1),
                       __builtin_shufflevector(kv, kv, 2, 3),
                       __builtin_shufflevector(kv, kv, 4, 5),
                       __builtin_shufflevector(kv, kv, 6, 7)};
        f32x2 v2[4] = {__builtin_shufflevector(va, va, 0, 1),
                       __builtin_shufflevector(va, va, 2, 3),
                       __builtin_shufflevector(vb, vb, 0, 1),
                       __builtin_shufflevector(vb, vb, 2, 3)};
#pragma unroll
        for (int q = 0; q < 4; ++q) {
            float s = bias4;
#pragma unroll
            for (int j = 0; j < 4; ++j) {
                h16x2 d2 = qr2[q][j] - k2[j];
                h16x2 r2 = __builtin_elementwise_max(d2, zh);
                s = fdot2f(w2[j], r2, s);
            }
            s += quad_swap1(s);
            s += quad_swap2(s);
            s = fmaxf(s, 0.f);
            const float e = EXP2F(s);
            l[q] += e;
            const f32x2 e2 = {e, e};
#pragma unroll
            for (int j = 0; j < 4; ++j) acc2[q][j] += e2 * v2[j];
        }
    };

    h16x8 kc = *(const h16x8*)kptr;
    f32x4 va = *(const f32x4*)vptr, vb = *(const f32x4*)(vptr + 4);
#pragma unroll 1
    for (int i = 0; i < 31; ++i) {
        kptr += 16 * 256; vptr += 16 * 256;
        h16x8 kn = *(const h16x8*)kptr;
        f32x4 va2 = *(const f32x4*)vptr, vb2 = *(const f32x4*)(vptr + 4);
        compute(kc, va, vb);
        kc = kn; va = va2; vb = vb2;
    }
    compute(kc, va, vb);

    // ---- epilogue: store 4 q + l, 16-phase LDS reduction, 2 outputs/thread --
    {
        float* rowp = &accbuf[p][lane32][0];
#pragma unroll
        for (int qq = 0; qq < 4; ++qq)
#pragma unroll
            for (int j = 0; j < 4; ++j)
                *(f32x2*)(rowp + qq * 8 + j * 2) = acc2[qq][j];
        if (dh == 0) {
#pragma unroll
            for (int qq = 0; qq < 4; ++qq) accbuf[p][lane32][32 + qq] = l[qq];
        }
    }
    __syncthreads();

    const int c_o = t & 255;
    const int g_o = c_o & 7, d_o = c_o >> 3;
    const int rowb = g_o * 4 + (d_o >> 3);
    const int colb = d_o & 7;
    const int qsel = t >> 8;                 // 0..1
#pragma unroll
    for (int h = 0; h < 2; ++h) {
        const int qh = qsel + 2 * h;         // 0..3
        float s = 0.f, ls = 0.f;
#pragma unroll
        for (int pp = 0; pp < 16; ++pp) {
            s  += accbuf[pp][rowb][qh * 8 + colb];
            ls += accbuf[pp][g_o * 4][32 + qh];
        }
        out[((size_t)(b * LL) + q0 + qh) * 256 + c_o] = s / ls;
    }
}

// ---------------------------------------------------------------------------
extern "C" void kernel_launch(void* const* d_in, const int* in_sizes, int n_in,
                              void* d_out, int out_size, void* d_ws, size_t ws_size,
                              hipStream_t stream) {
    (void)in_sizes; (void)n_in; (void)out_size; (void)ws_size;
    const float* x     = (const float*)d_in[0];
    const float* Wq    = (const float*)d_in[1];
    const float* Wk    = (const float*)d_in[2];
    const float* Wv    = (const float*)d_in[3];
    const float* w_mlp = (const float*)d_in[4];
    const float* b_mlp = (const float*)d_in[5];
    float* outp = (float*)d_out;

    _Float16* Qh = (_Float16*)d_ws;                            // 1 MB
    _Float16* Kh = (_Float16*)((char*)d_ws + (size_t)1048576); // 1 MB
    float*    Vt = (float*)((char*)d_ws + (size_t)2097152);    // 2 MB
    unsigned short* Xc = (unsigned short*)((char*)d_ws + (size_t)6291456);      // 3 MB
    unsigned short* Wc = (unsigned short*)((char*)d_ws + (size_t)6291456 + 3145728); // 1.125 MB

    split_bf16<<<dim3(M_ROWS + 768), 64, 0, stream>>>(x, Wq, Wk, Wv, Xc, Wc);
    qkv_mfma<<<dim3(384), 64, 0, stream>>>(Xc, Wc, Qh, Kh, Vt);
    attn_fused<<<dim3(512), 512, 0, stream>>>(Qh, Kh, Vt, w_mlp, b_mlp, outp);
}